// Round 8
// baseline (305.977 us; speedup 1.0000x reference)
//
#include <hip/hip_runtime.h>

#define DF 128
#define BN_EPS 1e-5f

typedef short s16x8 __attribute__((ext_vector_type(8)));
typedef float f32x4 __attribute__((ext_vector_type(4)));

// fp32 -> bf16 bits, round-to-nearest-even
__device__ __forceinline__ ushort f2b(float f) {
    uint u = __float_as_uint(f);
    u += 0x7fffu + ((u >> 16) & 1u);
    return (ushort)(u >> 16);
}
__device__ __forceinline__ float b2f_lo(uint v) { return __uint_as_float(v << 16); }
__device__ __forceinline__ float b2f_hi(uint v) { return __uint_as_float(v & 0xffff0000u); }

// ---------------------------------------------------------------------------
// prep: blocks 0..15 convert W/Wres -> bf16 Wcat; blocks 16+ histogram dst
// into bktcnt; the LAST-finishing histogram block performs the 1024-entry
// exclusive scan into bktptr/bktcur (removes the single-block scan kernel).
// ---------------------------------------------------------------------------
__global__ __launch_bounds__(512) void prep(
    const float* __restrict__ W, const float* __restrict__ Wres,
    ushort* __restrict__ Wcat, const int* __restrict__ dst,
    int* __restrict__ bktcnt, int* __restrict__ bktptr,
    int* __restrict__ bktcur, int* __restrict__ donecnt,
    int NBKT, int E, int nCnt)
{
    const int tid = threadIdx.x;
    if (blockIdx.x < 16) {
        // weight conversion: 16 blocks x 512 threads = 8192 float4s
        const float* src = (blockIdx.x < 8) ? W : Wres;
        ushort* dstp = Wcat + ((blockIdx.x < 8) ? 0 : 128 * DF);
        int t = (int)(blockIdx.x & 7) * 512 + tid;      // 0..4095
        float4 v = reinterpret_cast<const float4*>(src)[t];
        ushort4 o;
        o.x = f2b(v.x); o.y = f2b(v.y); o.z = f2b(v.z); o.w = f2b(v.w);
        reinterpret_cast<ushort4*>(dstp)[t] = o;
        return;
    }

    __shared__ int h[1024];
    const int cb = blockIdx.x - 16;
    for (int i = tid; i < 1024; i += 512) h[i] = 0;
    __syncthreads();
    const int base = cb * 4096;
#pragma unroll
    for (int k = 0; k < 2; ++k) {
        int i = base + k * 2048 + tid * 4;
        if (i + 3 < E) {
            int4 d = *reinterpret_cast<const int4*>(&dst[i]);
            atomicAdd(&h[d.x >> 6], 1);
            atomicAdd(&h[d.y >> 6], 1);
            atomicAdd(&h[d.z >> 6], 1);
            atomicAdd(&h[d.w >> 6], 1);
        } else {
            for (int j = 0; j < 4; ++j)
                if (i + j < E) atomicAdd(&h[dst[i + j] >> 6], 1);
        }
    }
    __syncthreads();
    for (int i = tid; i < 1024; i += 512)
        if (h[i]) atomicAdd(&bktcnt[i], h[i]);

    // last-block-done: perform the scan
    __threadfence();
    __shared__ int isLast;
    if (tid == 0) isLast = (atomicAdd(donecnt, 1) == nCnt - 1) ? 1 : 0;
    __syncthreads();
    if (!isLast) return;
    __threadfence();

    int v0 = (tid < NBKT) ? bktcnt[tid] : 0;
    int v1 = (tid + 512 < NBKT) ? bktcnt[tid + 512] : 0;
    h[tid] = v0; h[tid + 512] = v1;
    __syncthreads();
    for (int off = 1; off < 1024; off <<= 1) {
        int a0 = (tid >= off) ? h[tid - off] : 0;
        int a1 = (tid + 512 >= off) ? h[tid + 512 - off] : 0;
        __syncthreads();
        h[tid] += a0; h[tid + 512] += a1;
        __syncthreads();
    }
    if (tid < NBKT)       { int e = h[tid] - v0;       bktptr[tid] = e;       bktcur[tid] = e; }
    if (tid + 512 < NBKT) { int e = h[tid + 512] - v1; bktptr[tid + 512] = e; bktcur[tid + 512] = e; }
    if (tid == 0) bktptr[NBKT] = E;
}

// ---------------------------------------------------------------------------
// MFMA dual GEMM: support(bf16) = x@W^T + b ; res(fp32,d_out) = x@Wres^T + bres
// 32 rows per wave (two 16-row fragments share every W-fragment load).
// ---------------------------------------------------------------------------
__global__ __launch_bounds__(256) void gemm_mfma(
    const float* __restrict__ x, const ushort* __restrict__ Wcat,
    const float* __restrict__ b, const float* __restrict__ bres,
    ushort* __restrict__ support, float* __restrict__ res, int N)
{
    const int wave = threadIdx.x >> 6;
    const int lane = threadIdx.x & 63;
    const int base = (blockIdx.x * 4 + wave) * 32;
    if (base >= N) return;
    const int lrow = lane & 15;
    const int g4   = lane >> 4;        // 0..3
    const int koff = g4 * 8;
    const int row0 = base + lrow;
    const int row1 = base + 16 + lrow;
    const bool ok0 = row0 < N, ok1 = row1 < N;
    const int  a0r = ok0 ? row0 : (N - 1);
    const int  a1r = ok1 ? row1 : (N - 1);

    s16x8 xf0[4], xf1[4];
#pragma unroll
    for (int kb = 0; kb < 4; ++kb) {
        float4 f0 = reinterpret_cast<const float4*>(x)[(size_t)a0r * 32 + kb * 8 + g4 * 2];
        float4 f1 = reinterpret_cast<const float4*>(x)[(size_t)a0r * 32 + kb * 8 + g4 * 2 + 1];
        s16x8 v;
        v[0] = (short)f2b(f0.x); v[1] = (short)f2b(f0.y);
        v[2] = (short)f2b(f0.z); v[3] = (short)f2b(f0.w);
        v[4] = (short)f2b(f1.x); v[5] = (short)f2b(f1.y);
        v[6] = (short)f2b(f1.z); v[7] = (short)f2b(f1.w);
        xf0[kb] = v;
        float4 g0 = reinterpret_cast<const float4*>(x)[(size_t)a1r * 32 + kb * 8 + g4 * 2];
        float4 g1 = reinterpret_cast<const float4*>(x)[(size_t)a1r * 32 + kb * 8 + g4 * 2 + 1];
        s16x8 w;
        w[0] = (short)f2b(g0.x); w[1] = (short)f2b(g0.y);
        w[2] = (short)f2b(g0.z); w[3] = (short)f2b(g0.w);
        w[4] = (short)f2b(g1.x); w[5] = (short)f2b(g1.y);
        w[6] = (short)f2b(g1.z); w[7] = (short)f2b(g1.w);
        xf1[kb] = w;
    }

#pragma unroll
    for (int ct = 0; ct < 16; ++ct) {
        f32x4 acc0 = {0.f, 0.f, 0.f, 0.f};
        f32x4 acc1 = {0.f, 0.f, 0.f, 0.f};
#pragma unroll
        for (int kb = 0; kb < 4; ++kb) {
            s16x8 wf = *reinterpret_cast<const s16x8*>(
                &Wcat[(size_t)(ct * 16 + lrow) * 128 + kb * 32 + koff]);
            acc0 = __builtin_amdgcn_mfma_f32_16x16x32_bf16(wf, xf0[kb], acc0, 0, 0, 0);
            acc1 = __builtin_amdgcn_mfma_f32_16x16x32_bf16(wf, xf1[kb], acc1, 0, 0, 0);
        }
        int c0 = ct * 16 + 4 * g4;
        if (ct < 8) {
            float4 bias = *reinterpret_cast<const float4*>(&b[c0]);
            if (ok0) {
                ushort4 o;
                o.x = f2b(acc0[0] + bias.x); o.y = f2b(acc0[1] + bias.y);
                o.z = f2b(acc0[2] + bias.z); o.w = f2b(acc0[3] + bias.w);
                *reinterpret_cast<ushort4*>(&support[(size_t)row0 * 128 + c0]) = o;
            }
            if (ok1) {
                ushort4 o;
                o.x = f2b(acc1[0] + bias.x); o.y = f2b(acc1[1] + bias.y);
                o.z = f2b(acc1[2] + bias.z); o.w = f2b(acc1[3] + bias.w);
                *reinterpret_cast<ushort4*>(&support[(size_t)row1 * 128 + c0]) = o;
            }
        } else {
            int c = c0 - 128;
            float4 bias = *reinterpret_cast<const float4*>(&bres[c]);
            if (ok0) {
                float4 o = make_float4(acc0[0] + bias.x, acc0[1] + bias.y,
                                       acc0[2] + bias.z, acc0[3] + bias.w);
                *reinterpret_cast<float4*>(&res[(size_t)row0 * 128 + c]) = o;
            }
            if (ok1) {
                float4 o = make_float4(acc1[0] + bias.x, acc1[1] + bias.y,
                                       acc1[2] + bias.z, acc1[3] + bias.w);
                *reinterpret_cast<float4*>(&res[(size_t)row1 * 128 + c]) = o;
            }
        }
    }
}

// Record: word0 = src(16) | dstlocal(6)<<16 | bucket(10)<<22 ; word1 = fp32 w.
__global__ __launch_bounds__(512) void bin_scatter(
    const int* __restrict__ src, const int* __restrict__ dst,
    const float* __restrict__ ew, int* __restrict__ bktcur,
    uint2* __restrict__ recs, int E)
{
    __shared__ int cntl[1024];
    __shared__ int scn[1024];
    __shared__ int lcur[1024];
    __shared__ int gbase[1024];
    __shared__ uint2 stage[2048];
    const int tid = threadIdx.x;
    for (int i = tid; i < 1024; i += 512) cntl[i] = 0;
    __syncthreads();
    const int base = blockIdx.x * 2048;
    int myd[4];
#pragma unroll
    for (int k = 0; k < 4; ++k) {
        int i = base + k * 512 + tid;
        myd[k] = (i < E) ? dst[i] : -1;
        if (myd[k] >= 0) atomicAdd(&cntl[myd[k] >> 6], 1);
    }
    __syncthreads();
#pragma unroll
    for (int j = 0; j < 2; ++j) scn[tid + j * 512] = cntl[tid + j * 512];
    __syncthreads();
    for (int off = 1; off < 1024; off <<= 1) {
        int a[2];
#pragma unroll
        for (int j = 0; j < 2; ++j) {
            int idx = tid + j * 512;
            a[j] = (idx >= off) ? scn[idx - off] : 0;
        }
        __syncthreads();
#pragma unroll
        for (int j = 0; j < 2; ++j) scn[tid + j * 512] += a[j];
        __syncthreads();
    }
#pragma unroll
    for (int j = 0; j < 2; ++j) {
        int idx = tid + j * 512;
        int ex = scn[idx] - cntl[idx];
        scn[idx] = ex;
        lcur[idx] = ex;
    }
    for (int i = tid; i < 1024; i += 512) {
        int c = cntl[i];
        gbase[i] = c ? atomicAdd(&bktcur[i], c) : 0;
    }
    __syncthreads();
#pragma unroll
    for (int k = 0; k < 4; ++k) {
        int i = base + k * 512 + tid;
        if (i < E) {
            int d = myd[k];
            int bb = d >> 6;
            int p = atomicAdd(&lcur[bb], 1);
            uint w0 = (uint)src[i] | ((uint)(d & 63) << 16) | ((uint)bb << 22);
            stage[p] = make_uint2(w0, __float_as_uint(ew[i]));
        }
    }
    __syncthreads();
    const int nloc = min(2048, E - base);
    for (int j = tid; j < nloc; j += 512) {
        uint2 r = stage[j];
        int bb = r.x >> 22;
        int pos = gbase[bb] + (j - scn[bb]);
        recs[pos] = make_uint2(r.x & 0x3fffffu, r.y);
    }
}

// ---------------------------------------------------------------------------
// Half-bucket aggregation, atomic-free. 2 edges per load instruction: each
// half-wave (32 lanes x uint2 = 256B) gathers one support row. 16 edges per
// unrolled step = 8 loads in flight. Cross-half shfl_xor reduce at end.
// ---------------------------------------------------------------------------
#define ACC(A, vv, ww) { \
    A[0] = fmaf(b2f_lo((vv).x), (ww), A[0]); \
    A[1] = fmaf(b2f_hi((vv).x), (ww), A[1]); \
    A[2] = fmaf(b2f_lo((vv).y), (ww), A[2]); \
    A[3] = fmaf(b2f_hi((vv).y), (ww), A[3]); }

#define ROWLOOP(RR, A) { \
    const int r_ = wv * 4 + RR; \
    const int s0_ = hoff[r_]; \
    const int s1_ = s0_ + hcnt[r_]; \
    int k = s0_; \
    for (; k + 16 <= s1_; k += 16) { \
        uint2 e0 = sorted[k + hl],      e1 = sorted[k + 2 + hl]; \
        uint2 e2 = sorted[k + 4 + hl],  e3 = sorted[k + 6 + hl]; \
        uint2 e4 = sorted[k + 8 + hl],  e5 = sorted[k + 10 + hl]; \
        uint2 e6 = sorted[k + 12 + hl], e7 = sorted[k + 14 + hl]; \
        uint2 v0 = sup2[(size_t)(e0.x & 0xffffu) * 32 + cl]; \
        uint2 v1 = sup2[(size_t)(e1.x & 0xffffu) * 32 + cl]; \
        uint2 v2 = sup2[(size_t)(e2.x & 0xffffu) * 32 + cl]; \
        uint2 v3 = sup2[(size_t)(e3.x & 0xffffu) * 32 + cl]; \
        uint2 v4 = sup2[(size_t)(e4.x & 0xffffu) * 32 + cl]; \
        uint2 v5 = sup2[(size_t)(e5.x & 0xffffu) * 32 + cl]; \
        uint2 v6 = sup2[(size_t)(e6.x & 0xffffu) * 32 + cl]; \
        uint2 v7 = sup2[(size_t)(e7.x & 0xffffu) * 32 + cl]; \
        ACC(A, v0, __uint_as_float(e0.y)); ACC(A, v1, __uint_as_float(e1.y)); \
        ACC(A, v2, __uint_as_float(e2.y)); ACC(A, v3, __uint_as_float(e3.y)); \
        ACC(A, v4, __uint_as_float(e4.y)); ACC(A, v5, __uint_as_float(e5.y)); \
        ACC(A, v6, __uint_as_float(e6.y)); ACC(A, v7, __uint_as_float(e7.y)); \
    } \
    for (; k + 2 <= s1_; k += 2) { \
        uint2 e = sorted[k + hl]; \
        uint2 v = sup2[(size_t)(e.x & 0xffffu) * 32 + cl]; \
        ACC(A, v, __uint_as_float(e.y)); \
    } \
    if (k < s1_) { \
        uint2 e = sorted[k]; \
        uint2 v = sup2[(size_t)(e.x & 0xffffu) * 32 + cl]; \
        float w = hl ? 0.f : __uint_as_float(e.y); \
        ACC(A, v, w); \
    } }

__global__ __launch_bounds__(512) void spmm_sorted(
    const ushort* __restrict__ supportb, const uint2* __restrict__ recs,
    const int* __restrict__ bktptr, float* __restrict__ agg,
    float* __restrict__ bnacc, int N)
{
    __shared__ uint2 sorted[2048];     // 16 KB
    __shared__ int hcnt[32];
    __shared__ int hoff[32];
    __shared__ int hcur[32];

    const int tid  = threadIdx.x;
    const int wv   = tid >> 6;
    const int lane = tid & 63;
    const int hl   = lane >> 5;        // which edge of the pair
    const int cl   = lane & 31;        // column-quad
    const int b    = blockIdx.x >> 1;
    const int half = blockIdx.x & 1;
    const int beg  = bktptr[b], end = bktptr[b + 1];
    const uint2* sup2 = reinterpret_cast<const uint2*>(supportb);

    f32x4 acc0 = {0.f, 0.f, 0.f, 0.f};
    f32x4 acc1 = {0.f, 0.f, 0.f, 0.f};
    f32x4 acc2 = {0.f, 0.f, 0.f, 0.f};
    f32x4 acc3 = {0.f, 0.f, 0.f, 0.f};

    for (int cbeg = beg; cbeg < end; cbeg += 2048) {
        const int cn = min(2048, end - cbeg);
        if (tid < 32) hcnt[tid] = 0;
        __syncthreads();
        uint2 myr[4];
        bool  mv[4];
#pragma unroll
        for (int u = 0; u < 4; ++u) {
            int j = tid + u * 512;
            mv[u] = false;
            if (j < cn) {
                myr[u] = recs[cbeg + j];
                int dl = (myr[u].x >> 16) & 63;
                if ((dl >> 5) == half) {
                    mv[u] = true;
                    atomicAdd(&hcnt[dl & 31], 1);
                }
            }
        }
        __syncthreads();
        if (tid < 32) {
            int v = hcnt[tid];
            int inc = v;
#pragma unroll
            for (int off = 1; off < 32; off <<= 1) {
                int t = __shfl_up(inc, off, 32);
                if (tid >= off) inc += t;
            }
            hoff[tid] = inc - v;
            hcur[tid] = inc - v;
        }
        __syncthreads();
#pragma unroll
        for (int u = 0; u < 4; ++u) {
            if (mv[u]) {
                int r = (myr[u].x >> 16) & 31;
                int p = atomicAdd(&hcur[r], 1);
                sorted[p] = myr[u];
            }
        }
        __syncthreads();
        ROWLOOP(0, acc0)
        ROWLOOP(1, acc1)
        ROWLOOP(2, acc2)
        ROWLOOP(3, acc3)
        __syncthreads();
    }

    // cross-half reduce: lane l += lane l^32
#pragma unroll
    for (int j = 0; j < 4; ++j) {
        acc0[j] += __shfl_xor(acc0[j], 32, 64);
        acc1[j] += __shfl_xor(acc1[j], 32, 64);
        acc2[j] += __shfl_xor(acc2[j], 32, 64);
        acc3[j] += __shfl_xor(acc3[j], 32, 64);
    }

    // write agg rows (lanes 0-31: 32 x float4 = 512B per row)
    const int row0 = b * 64 + half * 32 + wv * 4;
    if (hl == 0) {
        if (row0 + 0 < N) *reinterpret_cast<f32x4*>(&agg[(size_t)(row0 + 0) * 128 + cl * 4]) = acc0;
        if (row0 + 1 < N) *reinterpret_cast<f32x4*>(&agg[(size_t)(row0 + 1) * 128 + cl * 4]) = acc1;
        if (row0 + 2 < N) *reinterpret_cast<f32x4*>(&agg[(size_t)(row0 + 2) * 128 + cl * 4]) = acc2;
        if (row0 + 3 < N) *reinterpret_cast<f32x4*>(&agg[(size_t)(row0 + 3) * 128 + cl * 4]) = acc3;
    }

    // BN column partials (rows >= N hold zeros, contribute nothing)
    f32x4 s1v = acc0 + acc1 + acc2 + acc3;
    f32x4 s2v = acc0 * acc0 + acc1 * acc1 + acc2 * acc2 + acc3 * acc3;
    float* redf = reinterpret_cast<float*>(sorted);   // reuse 16KB LDS
    if (hl == 0) {
        *reinterpret_cast<f32x4*>(&redf[wv * 128 + cl * 4]) = s1v;
        *reinterpret_cast<f32x4*>(&redf[1024 + wv * 128 + cl * 4]) = s2v;
    }
    __syncthreads();
    if (tid < 128) {
        float t1 = 0.f, t2 = 0.f;
#pragma unroll
        for (int w8 = 0; w8 < 8; ++w8) {
            t1 += redf[w8 * 128 + tid];
            t2 += redf[1024 + w8 * 128 + tid];
        }
        unsafeAtomicAdd(&bnacc[tid], t1);
        unsafeAtomicAdd(&bnacc[128 + tid], t2);
    }
}

// ---------------------------------------------------------------------------
// out = relu(agg*scale + shift) + res, with BN finalize inlined per block.
// ---------------------------------------------------------------------------
__global__ __launch_bounds__(256) void bn_apply(
    const float* __restrict__ agg, const float* __restrict__ bnacc,
    const float* __restrict__ gamma, const float* __restrict__ beta,
    float* __restrict__ out, float invN, long total4)
{
    __shared__ float s_sc[128], s_sh[128];
    const int tid = threadIdx.x;
    if (tid < 128) {
        float mean = bnacc[tid] * invN;
        float var  = bnacc[128 + tid] * invN - mean * mean;
        float sc   = gamma[tid] * rsqrtf(var + BN_EPS);
        s_sc[tid] = sc;
        s_sh[tid] = beta[tid] - mean * sc;
    }
    __syncthreads();
    long t = (long)blockIdx.x * 256 + tid;
    if (t >= total4) return;
    int f4 = (int)(t & 31);
    float4 v  = reinterpret_cast<const float4*>(agg)[t];
    float4 sc = reinterpret_cast<const float4*>(s_sc)[f4];
    float4 sh = reinterpret_cast<const float4*>(s_sh)[f4];
    float4 r  = reinterpret_cast<float4*>(out)[t];
    float4 o;
    o.x = fmaxf(fmaf(v.x, sc.x, sh.x), 0.f) + r.x;
    o.y = fmaxf(fmaf(v.y, sc.y, sh.y), 0.f) + r.y;
    o.z = fmaxf(fmaf(v.z, sc.z, sh.z), 0.f) + r.z;
    o.w = fmaxf(fmaf(v.w, sc.w, sh.w), 0.f) + r.w;
    reinterpret_cast<float4*>(out)[t] = o;
}

// ---------------------------------------------------------------------------
extern "C" void kernel_launch(void* const* d_in, const int* in_sizes, int n_in,
                              void* d_out, int out_size, void* d_ws, size_t ws_size,
                              hipStream_t stream)
{
    const float* x     = (const float*)d_in[0];
    const int*   ei    = (const int*)  d_in[1];
    const float* ew    = (const float*)d_in[2];
    const float* W     = (const float*)d_in[3];
    const float* b     = (const float*)d_in[4];
    const float* Wres  = (const float*)d_in[5];
    const float* bres  = (const float*)d_in[6];
    const float* gamma = (const float*)d_in[7];
    const float* beta  = (const float*)d_in[8];

    const int N = in_sizes[0] / DF;
    const int E = in_sizes[2];
    const int* srci = ei;          // edge_index[0]
    const int* dsti = ei + E;      // edge_index[1]
    const int NBKT = (N + 63) >> 6;            // <=1024 by construction

    // ws layout (4B words):
    // agg[N*128] | bnacc[256] | bktcnt[1056] | donecnt[32] | bktptr[1056] |
    // bktcur[1056] | supportb[N*64w] | recs[E*2w] | Wcat[8192w]
    float*  fws      = (float*)d_ws;
    float*  agg      = fws;
    float*  bnacc    = agg + (size_t)N * DF;
    int*    bktcnt   = (int*)(bnacc + 256);
    int*    donecnt  = bktcnt + 1056;
    int*    bktptr   = donecnt + 32;
    int*    bktcur   = bktptr + 1056;
    ushort* supportb = (ushort*)(bktcur + 1056);
    uint2*  recs     = (uint2*)(supportb + (size_t)N * DF);
    ushort* Wcat     = (ushort*)(recs + (size_t)E);
    float*  out      = (float*)d_out;

    // zero bnacc + bktcnt + donecnt (contiguous)
    hipMemsetAsync(bnacc, 0, (256 + 1056 + 32) * sizeof(float), stream);

    const int nCnt = (E + 4095) / 4096;
    prep<<<16 + nCnt, 512, 0, stream>>>(W, Wres, Wcat, dsti, bktcnt, bktptr,
                                        bktcur, donecnt, NBKT, E, nCnt);

    gemm_mfma<<<(N + 127) / 128, 256, 0, stream>>>(x, Wcat, b, bres, supportb, out, N);

    bin_scatter<<<(E + 2047) / 2048, 512, 0, stream>>>(srci, dsti, ew, bktcur, recs, E);

    spmm_sorted<<<NBKT * 2, 512, 0, stream>>>(supportb, recs, bktptr, agg, bnacc, N);

    long t4 = (long)N * (DF / 4);
    bn_apply<<<(int)((t4 + 255) / 256), 256, 0, stream>>>(
        agg, bnacc, gamma, beta, out, 1.0f / (float)N, t4);
}

// Round 9
// 226.346 us; speedup vs baseline: 1.3518x; 1.3518x over previous
//
#include <hip/hip_runtime.h>

#define DF 128
#define BN_EPS 1e-5f

typedef short s16x8 __attribute__((ext_vector_type(8)));
typedef float f32x4 __attribute__((ext_vector_type(4)));

// fp32 -> bf16 bits, round-to-nearest-even
__device__ __forceinline__ ushort f2b(float f) {
    uint u = __float_as_uint(f);
    u += 0x7fffu + ((u >> 16) & 1u);
    return (ushort)(u >> 16);
}
__device__ __forceinline__ float b2f_lo(uint v) { return __uint_as_float(v << 16); }
__device__ __forceinline__ float b2f_hi(uint v) { return __uint_as_float(v & 0xffff0000u); }

// ---------------------------------------------------------------------------
// prep: blocks 0..15 convert W/Wres -> bf16 Wcat; blocks 16+ histogram dst.
// (scan stays a separate kernel -- R8 showed in-kernel scan fusion regresses)
// ---------------------------------------------------------------------------
__global__ __launch_bounds__(512) void prep(
    const float* __restrict__ W, const float* __restrict__ Wres,
    ushort* __restrict__ Wcat, const int* __restrict__ dst,
    int* __restrict__ bktcnt, int E)
{
    const int tid = threadIdx.x;
    if (blockIdx.x < 16) {
        const float* src = (blockIdx.x < 8) ? W : Wres;
        ushort* dstp = Wcat + ((blockIdx.x < 8) ? 0 : 128 * DF);
        int t = (int)(blockIdx.x & 7) * 512 + tid;      // 0..4095 float4s
        float4 v = reinterpret_cast<const float4*>(src)[t];
        ushort4 o;
        o.x = f2b(v.x); o.y = f2b(v.y); o.z = f2b(v.z); o.w = f2b(v.w);
        reinterpret_cast<ushort4*>(dstp)[t] = o;
        return;
    }
    __shared__ int h[1024];
    const int cb = blockIdx.x - 16;
    for (int i = tid; i < 1024; i += 512) h[i] = 0;
    __syncthreads();
    const int base = cb * 4096;
#pragma unroll
    for (int k = 0; k < 2; ++k) {
        int i = base + k * 2048 + tid * 4;
        if (i + 3 < E) {
            int4 d = *reinterpret_cast<const int4*>(&dst[i]);
            atomicAdd(&h[d.x >> 6], 1);
            atomicAdd(&h[d.y >> 6], 1);
            atomicAdd(&h[d.z >> 6], 1);
            atomicAdd(&h[d.w >> 6], 1);
        } else {
            for (int j = 0; j < 4; ++j)
                if (i + j < E) atomicAdd(&h[dst[i + j] >> 6], 1);
        }
    }
    __syncthreads();
    for (int i = tid; i < 1024; i += 512)
        if (h[i]) atomicAdd(&bktcnt[i], h[i]);
}

__global__ __launch_bounds__(512) void bin_scan(
    const int* __restrict__ bktcnt, int* __restrict__ bktptr,
    int* __restrict__ bktcur, int NBKT, int E)
{
    __shared__ int s[1024];
    const int t = threadIdx.x;
    int v0 = (t < NBKT) ? bktcnt[t] : 0;
    int v1 = (t + 512 < NBKT) ? bktcnt[t + 512] : 0;
    s[t] = v0; s[t + 512] = v1;
    __syncthreads();
    for (int off = 1; off < 1024; off <<= 1) {
        int a0 = (t >= off) ? s[t - off] : 0;
        int a1 = (t + 512 >= off) ? s[t + 512 - off] : 0;
        __syncthreads();
        s[t] += a0; s[t + 512] += a1;
        __syncthreads();
    }
    if (t < NBKT)       { int e = s[t] - v0;       bktptr[t] = e;       bktcur[t] = e; }
    if (t + 512 < NBKT) { int e = s[t+512] - v1;   bktptr[t+512] = e;   bktcur[t+512] = e; }
    if (t == 0) bktptr[NBKT] = E;
}

// ---------------------------------------------------------------------------
// Fused: blocks [0, gemmB) = MFMA dual GEMM (8 waves x 32 rows = 256 rows);
// blocks [gemmB, ...) = bin_scatter (tile 2048). Independent work, runs
// concurrently -> the smaller hides under the larger.
// ---------------------------------------------------------------------------
__global__ __launch_bounds__(512) void gemm_scatter(
    const float* __restrict__ x, const ushort* __restrict__ Wcat,
    const float* __restrict__ b, const float* __restrict__ bres,
    ushort* __restrict__ support, float* __restrict__ res, int N, int gemmB,
    const int* __restrict__ src, const int* __restrict__ dst,
    const float* __restrict__ ew, int* __restrict__ bktcur,
    uint2* __restrict__ recs, int E)
{
    __shared__ int cntl[1024];
    __shared__ int scn[1024];
    __shared__ int lcur[1024];
    __shared__ int gbase[1024];
    __shared__ uint2 stage[2048];

    const int tid = threadIdx.x;

    if ((int)blockIdx.x < gemmB) {
        // ---------------- GEMM part ----------------
        const int wave = tid >> 6;
        const int lane = tid & 63;
        const int base = ((int)blockIdx.x * 8 + wave) * 32;
        if (base >= N) return;
        const int lrow = lane & 15;
        const int g4   = lane >> 4;
        const int koff = g4 * 8;
        const int row0 = base + lrow;
        const int row1 = base + 16 + lrow;
        const bool ok0 = row0 < N, ok1 = row1 < N;
        const int  a0r = ok0 ? row0 : (N - 1);
        const int  a1r = ok1 ? row1 : (N - 1);

        s16x8 xf0[4], xf1[4];
#pragma unroll
        for (int kb = 0; kb < 4; ++kb) {
            float4 f0 = reinterpret_cast<const float4*>(x)[(size_t)a0r * 32 + kb * 8 + g4 * 2];
            float4 f1 = reinterpret_cast<const float4*>(x)[(size_t)a0r * 32 + kb * 8 + g4 * 2 + 1];
            s16x8 v;
            v[0] = (short)f2b(f0.x); v[1] = (short)f2b(f0.y);
            v[2] = (short)f2b(f0.z); v[3] = (short)f2b(f0.w);
            v[4] = (short)f2b(f1.x); v[5] = (short)f2b(f1.y);
            v[6] = (short)f2b(f1.z); v[7] = (short)f2b(f1.w);
            xf0[kb] = v;
            float4 g0 = reinterpret_cast<const float4*>(x)[(size_t)a1r * 32 + kb * 8 + g4 * 2];
            float4 g1 = reinterpret_cast<const float4*>(x)[(size_t)a1r * 32 + kb * 8 + g4 * 2 + 1];
            s16x8 w;
            w[0] = (short)f2b(g0.x); w[1] = (short)f2b(g0.y);
            w[2] = (short)f2b(g0.z); w[3] = (short)f2b(g0.w);
            w[4] = (short)f2b(g1.x); w[5] = (short)f2b(g1.y);
            w[6] = (short)f2b(g1.z); w[7] = (short)f2b(g1.w);
            xf1[kb] = w;
        }

#pragma unroll
        for (int ct = 0; ct < 16; ++ct) {
            f32x4 acc0 = {0.f, 0.f, 0.f, 0.f};
            f32x4 acc1 = {0.f, 0.f, 0.f, 0.f};
#pragma unroll
            for (int kb = 0; kb < 4; ++kb) {
                s16x8 wf = *reinterpret_cast<const s16x8*>(
                    &Wcat[(size_t)(ct * 16 + lrow) * 128 + kb * 32 + koff]);
                acc0 = __builtin_amdgcn_mfma_f32_16x16x32_bf16(wf, xf0[kb], acc0, 0, 0, 0);
                acc1 = __builtin_amdgcn_mfma_f32_16x16x32_bf16(wf, xf1[kb], acc1, 0, 0, 0);
            }
            int c0 = ct * 16 + 4 * g4;
            if (ct < 8) {
                float4 bias = *reinterpret_cast<const float4*>(&b[c0]);
                if (ok0) {
                    ushort4 o;
                    o.x = f2b(acc0[0] + bias.x); o.y = f2b(acc0[1] + bias.y);
                    o.z = f2b(acc0[2] + bias.z); o.w = f2b(acc0[3] + bias.w);
                    *reinterpret_cast<ushort4*>(&support[(size_t)row0 * 128 + c0]) = o;
                }
                if (ok1) {
                    ushort4 o;
                    o.x = f2b(acc1[0] + bias.x); o.y = f2b(acc1[1] + bias.y);
                    o.z = f2b(acc1[2] + bias.z); o.w = f2b(acc1[3] + bias.w);
                    *reinterpret_cast<ushort4*>(&support[(size_t)row1 * 128 + c0]) = o;
                }
            } else {
                int c = c0 - 128;
                float4 bias = *reinterpret_cast<const float4*>(&bres[c]);
                if (ok0) {
                    float4 o = make_float4(acc0[0] + bias.x, acc0[1] + bias.y,
                                           acc0[2] + bias.z, acc0[3] + bias.w);
                    *reinterpret_cast<float4*>(&res[(size_t)row0 * 128 + c]) = o;
                }
                if (ok1) {
                    float4 o = make_float4(acc1[0] + bias.x, acc1[1] + bias.y,
                                           acc1[2] + bias.z, acc1[3] + bias.w);
                    *reinterpret_cast<float4*>(&res[(size_t)row1 * 128 + c]) = o;
                }
            }
        }
        return;
    }

    // ---------------- scatter part ----------------
    const int cb = (int)blockIdx.x - gemmB;
    for (int i = tid; i < 1024; i += 512) cntl[i] = 0;
    __syncthreads();
    const int base = cb * 2048;
    int myd[4];
#pragma unroll
    for (int k = 0; k < 4; ++k) {
        int i = base + k * 512 + tid;
        myd[k] = (i < E) ? dst[i] : -1;
        if (myd[k] >= 0) atomicAdd(&cntl[myd[k] >> 6], 1);
    }
    __syncthreads();
#pragma unroll
    for (int j = 0; j < 2; ++j) scn[tid + j * 512] = cntl[tid + j * 512];
    __syncthreads();
    for (int off = 1; off < 1024; off <<= 1) {
        int a[2];
#pragma unroll
        for (int j = 0; j < 2; ++j) {
            int idx = tid + j * 512;
            a[j] = (idx >= off) ? scn[idx - off] : 0;
        }
        __syncthreads();
#pragma unroll
        for (int j = 0; j < 2; ++j) scn[tid + j * 512] += a[j];
        __syncthreads();
    }
#pragma unroll
    for (int j = 0; j < 2; ++j) {
        int idx = tid + j * 512;
        int ex = scn[idx] - cntl[idx];
        scn[idx] = ex;
        lcur[idx] = ex;
    }
    for (int i = tid; i < 1024; i += 512) {
        int c = cntl[i];
        gbase[i] = c ? atomicAdd(&bktcur[i], c) : 0;
    }
    __syncthreads();
#pragma unroll
    for (int k = 0; k < 4; ++k) {
        int i = base + k * 512 + tid;
        if (i < E) {
            int d = myd[k];
            int bb = d >> 6;
            int p = atomicAdd(&lcur[bb], 1);
            uint w0 = (uint)src[i] | ((uint)(d & 63) << 16) | ((uint)bb << 22);
            stage[p] = make_uint2(w0, __float_as_uint(ew[i]));
        }
    }
    __syncthreads();
    const int nloc = min(2048, E - base);
    for (int j = tid; j < nloc; j += 512) {
        uint2 r = stage[j];
        int bb = r.x >> 22;
        int pos = gbase[bb] + (j - scn[bb]);
        recs[pos] = make_uint2(r.x & 0x3fffffu, r.y);
    }
}

// ---------------------------------------------------------------------------
// Half-bucket aggregation, atomic-free, unroll-8 gathers (R7-proven: VGPR 32,
// occupancy ~61%). Fuses BN column partials.
// ---------------------------------------------------------------------------
__global__ __launch_bounds__(512) void spmm_sorted(
    const ushort* __restrict__ supportb, const uint2* __restrict__ recs,
    const int* __restrict__ bktptr, float* __restrict__ agg,
    float* __restrict__ bnacc, int N)
{
    __shared__ uint2 sorted[2048];     // 16 KB
    __shared__ int hcnt[32];
    __shared__ int hoff[32];
    __shared__ int hcur[32];

    const int tid  = threadIdx.x;
    const int wv   = tid >> 6;
    const int lane = tid & 63;
    const int b    = blockIdx.x >> 1;
    const int half = blockIdx.x & 1;
    const int beg  = bktptr[b], end = bktptr[b + 1];
    const uint* sup = reinterpret_cast<const uint*>(supportb);

    float ax[4], ay[4];
#pragma unroll
    for (int r = 0; r < 4; ++r) { ax[r] = 0.f; ay[r] = 0.f; }

    for (int cbeg = beg; cbeg < end; cbeg += 2048) {
        const int cn = min(2048, end - cbeg);
        if (tid < 32) hcnt[tid] = 0;
        __syncthreads();
        uint2 myr[4];
        bool  mv[4];
#pragma unroll
        for (int u = 0; u < 4; ++u) {
            int j = tid + u * 512;
            mv[u] = false;
            if (j < cn) {
                myr[u] = recs[cbeg + j];
                int dl = (myr[u].x >> 16) & 63;
                if ((dl >> 5) == half) {
                    mv[u] = true;
                    atomicAdd(&hcnt[dl & 31], 1);
                }
            }
        }
        __syncthreads();
        if (tid < 32) {
            int v = hcnt[tid];
            int inc = v;
#pragma unroll
            for (int off = 1; off < 32; off <<= 1) {
                int t = __shfl_up(inc, off, 32);
                if (tid >= off) inc += t;
            }
            hoff[tid] = inc - v;
            hcur[tid] = inc - v;
        }
        __syncthreads();
#pragma unroll
        for (int u = 0; u < 4; ++u) {
            if (mv[u]) {
                int r = (myr[u].x >> 16) & 31;
                int p = atomicAdd(&hcur[r], 1);
                sorted[p] = myr[u];
            }
        }
        __syncthreads();
        // compute: wave wv owns local rows wv*4 .. wv*4+3
#pragma unroll
        for (int rr = 0; rr < 4; ++rr) {
            const int r  = wv * 4 + rr;
            const int s0 = hoff[r];
            const int s1 = s0 + hcnt[r];
            int k = s0;
            for (; k + 8 <= s1; k += 8) {
                uint2 e0 = sorted[k],   e1 = sorted[k+1], e2 = sorted[k+2], e3 = sorted[k+3];
                uint2 e4 = sorted[k+4], e5 = sorted[k+5], e6 = sorted[k+6], e7 = sorted[k+7];
                uint v0 = sup[(size_t)(e0.x & 0xffffu) * 64 + lane];
                uint v1 = sup[(size_t)(e1.x & 0xffffu) * 64 + lane];
                uint v2 = sup[(size_t)(e2.x & 0xffffu) * 64 + lane];
                uint v3 = sup[(size_t)(e3.x & 0xffffu) * 64 + lane];
                uint v4 = sup[(size_t)(e4.x & 0xffffu) * 64 + lane];
                uint v5 = sup[(size_t)(e5.x & 0xffffu) * 64 + lane];
                uint v6 = sup[(size_t)(e6.x & 0xffffu) * 64 + lane];
                uint v7 = sup[(size_t)(e7.x & 0xffffu) * 64 + lane];
                float w0 = __uint_as_float(e0.y), w1 = __uint_as_float(e1.y);
                float w2 = __uint_as_float(e2.y), w3 = __uint_as_float(e3.y);
                float w4 = __uint_as_float(e4.y), w5 = __uint_as_float(e5.y);
                float w6 = __uint_as_float(e6.y), w7 = __uint_as_float(e7.y);
                ax[rr] = fmaf(b2f_lo(v0), w0, ax[rr]); ay[rr] = fmaf(b2f_hi(v0), w0, ay[rr]);
                ax[rr] = fmaf(b2f_lo(v1), w1, ax[rr]); ay[rr] = fmaf(b2f_hi(v1), w1, ay[rr]);
                ax[rr] = fmaf(b2f_lo(v2), w2, ax[rr]); ay[rr] = fmaf(b2f_hi(v2), w2, ay[rr]);
                ax[rr] = fmaf(b2f_lo(v3), w3, ax[rr]); ay[rr] = fmaf(b2f_hi(v3), w3, ay[rr]);
                ax[rr] = fmaf(b2f_lo(v4), w4, ax[rr]); ay[rr] = fmaf(b2f_hi(v4), w4, ay[rr]);
                ax[rr] = fmaf(b2f_lo(v5), w5, ax[rr]); ay[rr] = fmaf(b2f_hi(v5), w5, ay[rr]);
                ax[rr] = fmaf(b2f_lo(v6), w6, ax[rr]); ay[rr] = fmaf(b2f_hi(v6), w6, ay[rr]);
                ax[rr] = fmaf(b2f_lo(v7), w7, ax[rr]); ay[rr] = fmaf(b2f_hi(v7), w7, ay[rr]);
            }
            for (; k + 4 <= s1; k += 4) {
                uint2 e0 = sorted[k], e1 = sorted[k+1], e2 = sorted[k+2], e3 = sorted[k+3];
                uint v0 = sup[(size_t)(e0.x & 0xffffu) * 64 + lane];
                uint v1 = sup[(size_t)(e1.x & 0xffffu) * 64 + lane];
                uint v2 = sup[(size_t)(e2.x & 0xffffu) * 64 + lane];
                uint v3 = sup[(size_t)(e3.x & 0xffffu) * 64 + lane];
                float w0 = __uint_as_float(e0.y), w1 = __uint_as_float(e1.y);
                float w2 = __uint_as_float(e2.y), w3 = __uint_as_float(e3.y);
                ax[rr] = fmaf(b2f_lo(v0), w0, ax[rr]); ay[rr] = fmaf(b2f_hi(v0), w0, ay[rr]);
                ax[rr] = fmaf(b2f_lo(v1), w1, ax[rr]); ay[rr] = fmaf(b2f_hi(v1), w1, ay[rr]);
                ax[rr] = fmaf(b2f_lo(v2), w2, ax[rr]); ay[rr] = fmaf(b2f_hi(v2), w2, ay[rr]);
                ax[rr] = fmaf(b2f_lo(v3), w3, ax[rr]); ay[rr] = fmaf(b2f_hi(v3), w3, ay[rr]);
            }
            for (; k < s1; ++k) {
                uint2 e = sorted[k];
                uint v = sup[(size_t)(e.x & 0xffffu) * 64 + lane];
                float w = __uint_as_float(e.y);
                ax[rr] = fmaf(b2f_lo(v), w, ax[rr]);
                ay[rr] = fmaf(b2f_hi(v), w, ay[rr]);
            }
        }
        __syncthreads();
    }

    // write agg rows (coalesced float2)
    const int row0 = b * 64 + half * 32 + wv * 4;
#pragma unroll
    for (int rr = 0; rr < 4; ++rr) {
        int gr = row0 + rr;
        if (gr < N)
            reinterpret_cast<float2*>(agg)[(size_t)gr * 64 + lane] = make_float2(ax[rr], ay[rr]);
    }

    // BN column partials (rows >= N hold zeros, contribute nothing)
    float s1x = 0.f, s1y = 0.f, s2x = 0.f, s2y = 0.f;
#pragma unroll
    for (int rr = 0; rr < 4; ++rr) {
        s1x += ax[rr]; s1y += ay[rr];
        s2x = fmaf(ax[rr], ax[rr], s2x);
        s2y = fmaf(ay[rr], ay[rr], s2y);
    }
    float* red = reinterpret_cast<float*>(sorted);   // reuse 16KB LDS
    red[wv * 256 + 2 * lane]            = s1x;
    red[wv * 256 + 2 * lane + 1]        = s1y;
    red[2048 + wv * 256 + 2 * lane]     = s2x;
    red[2048 + wv * 256 + 2 * lane + 1] = s2y;
    __syncthreads();
    if (tid < 128) {
        float t1 = 0.f, t2 = 0.f;
#pragma unroll
        for (int w8 = 0; w8 < 8; ++w8) {
            t1 += red[w8 * 256 + tid];
            t2 += red[2048 + w8 * 256 + tid];
        }
        unsafeAtomicAdd(&bnacc[tid], t1);
        unsafeAtomicAdd(&bnacc[128 + tid], t2);
    }
}

// ---------------------------------------------------------------------------
// out = relu(agg*scale + shift) + res, with BN finalize inlined per block.
// ---------------------------------------------------------------------------
__global__ __launch_bounds__(256) void bn_apply(
    const float* __restrict__ agg, const float* __restrict__ bnacc,
    const float* __restrict__ gamma, const float* __restrict__ beta,
    float* __restrict__ out, float invN, long total4)
{
    __shared__ float s_sc[128], s_sh[128];
    const int tid = threadIdx.x;
    if (tid < 128) {
        float mean = bnacc[tid] * invN;
        float var  = bnacc[128 + tid] * invN - mean * mean;
        float sc   = gamma[tid] * rsqrtf(var + BN_EPS);
        s_sc[tid] = sc;
        s_sh[tid] = beta[tid] - mean * sc;
    }
    __syncthreads();
    long t = (long)blockIdx.x * 256 + tid;
    if (t >= total4) return;
    int f4 = (int)(t & 31);
    float4 v  = reinterpret_cast<const float4*>(agg)[t];
    float4 sc = reinterpret_cast<const float4*>(s_sc)[f4];
    float4 sh = reinterpret_cast<const float4*>(s_sh)[f4];
    float4 r  = reinterpret_cast<float4*>(out)[t];
    float4 o;
    o.x = fmaxf(fmaf(v.x, sc.x, sh.x), 0.f) + r.x;
    o.y = fmaxf(fmaf(v.y, sc.y, sh.y), 0.f) + r.y;
    o.z = fmaxf(fmaf(v.z, sc.z, sh.z), 0.f) + r.z;
    o.w = fmaxf(fmaf(v.w, sc.w, sh.w), 0.f) + r.w;
    reinterpret_cast<float4*>(out)[t] = o;
}

// ---------------------------------------------------------------------------
extern "C" void kernel_launch(void* const* d_in, const int* in_sizes, int n_in,
                              void* d_out, int out_size, void* d_ws, size_t ws_size,
                              hipStream_t stream)
{
    const float* x     = (const float*)d_in[0];
    const int*   ei    = (const int*)  d_in[1];
    const float* ew    = (const float*)d_in[2];
    const float* W     = (const float*)d_in[3];
    const float* b     = (const float*)d_in[4];
    const float* Wres  = (const float*)d_in[5];
    const float* bres  = (const float*)d_in[6];
    const float* gamma = (const float*)d_in[7];
    const float* beta  = (const float*)d_in[8];

    const int N = in_sizes[0] / DF;
    const int E = in_sizes[2];
    const int* srci = ei;          // edge_index[0]
    const int* dsti = ei + E;      // edge_index[1]
    const int NBKT = (N + 63) >> 6;            // <=1024 by construction

    // ws layout (4B words):
    // agg[N*128] | bnacc[256] | bktcnt[1056] | bktptr[1056] | bktcur[1056] |
    // supportb[N*64w] | recs[E*2w] | Wcat[8192w]
    float*  fws      = (float*)d_ws;
    float*  agg      = fws;
    float*  bnacc    = agg + (size_t)N * DF;
    int*    bktcnt   = (int*)(bnacc + 256);
    int*    bktptr   = bktcnt + 1056;
    int*    bktcur   = bktptr + 1056;
    ushort* supportb = (ushort*)(bktcur + 1056);
    uint2*  recs     = (uint2*)(supportb + (size_t)N * DF);
    ushort* Wcat     = (ushort*)(recs + (size_t)E);
    float*  out      = (float*)d_out;

    // zero bnacc + bktcnt (contiguous)
    hipMemsetAsync(bnacc, 0, (256 + 1056) * sizeof(float), stream);

    const int nHist = (E + 4095) / 4096;
    prep<<<16 + nHist, 512, 0, stream>>>(W, Wres, Wcat, dsti, bktcnt, E);

    bin_scan<<<1, 512, 0, stream>>>(bktcnt, bktptr, bktcur, NBKT, E);

    const int gemmB = (N + 255) / 256;
    const int scatB = (E + 2047) / 2048;
    gemm_scatter<<<gemmB + scatB, 512, 0, stream>>>(
        x, Wcat, b, bres, supportb, out, N, gemmB,
        srci, dsti, ew, bktcur, recs, E);

    spmm_sorted<<<NBKT * 2, 512, 0, stream>>>(supportb, recs, bktptr, agg, bnacc, N);

    long t4 = (long)N * (DF / 4);
    bn_apply<<<(int)((t4 + 255) / 256), 256, 0, stream>>>(
        agg, bnacc, gamma, beta, out, 1.0f / (float)N, t4);
}